// Round 1
// baseline (240714.990 us; speedup 1.0000x reference)
//
#include <hip/hip_runtime.h>
#include <hip/hip_bf16.h>

// Problem constants
#define B_   32
#define T_   2000
#define H_   896
#define SUB_ 448
#define Q_   256

// Scan decomposition: 256 blocks = 32 seq x 8 slices, 1024 thr = 16 waves
#define NS_  8            // slices (blocks) per sequence
#define JS_  112          // h-columns per slice (H/NS)
#define NW_  16           // waves per block
#define KCH_ 56           // k-chunk per wave (H/NW)

// d_out layout (floats): ct [32,2000,256], ft [32,2000,256], last [32,1,896]
#define FT_OFF   16384000
#define LAST_OFF 32768000

// d_ws layout (bytes)
#define HBUF_FLOATS  (2*B_*H_)            // 57344 floats
#define FLAGS_BOFF   (HBUF_FLOATS*4)      // 229376
#define STATES_BOFF  262144               // bf16 states [32][2000][896] -> ~114.7MB

__device__ __forceinline__ float bf2f(unsigned short u) {
    union { unsigned int i; float f; } v; v.i = ((unsigned int)u) << 16; return v.f;
}

// ---------------------------------------------------------------------------
// init: hbuf[0] = state, flags = 0
// ---------------------------------------------------------------------------
__global__ void wavrnn_init(const float* __restrict__ state,
                            float* __restrict__ hbuf,
                            int* __restrict__ flags) {
    const int i = blockIdx.x * 256 + threadIdx.x;
    if (i < B_ * H_) hbuf[i] = state[i];
    const int f = i - B_ * H_;
    if (f >= 0 && f < B_ * NS_) flags[f] = 0;
}

// ---------------------------------------------------------------------------
// scan: persistent per-(seq,slice) blocks, register-resident R slice.
// ---------------------------------------------------------------------------
__global__ __launch_bounds__(1024, 4)
void wavrnn_scan(const int* __restrict__ sample, const int* __restrict__ cts,
                 const float* __restrict__ R,
                 const float* __restrict__ Wc, const float* __restrict__ Wf,
                 const float* __restrict__ b_u, const float* __restrict__ b_r,
                 const float* __restrict__ b_e,
                 float* __restrict__ hbuf,            // [2][B][H]
                 int* __restrict__ flags,             // [B][NS]
                 __hip_bfloat16* __restrict__ states, // [B][T][H]
                 float* __restrict__ out)             // d_out (last region)
{
    const int tid  = (int)threadIdx.x;
    const int w    = tid >> 6;       // wave 0..15  -> k chunk
    const int lane = tid & 63;       // lane: j pair (lanes 0..55 valid)
    const int s    = (int)blockIdx.x >> 3;
    const int x    = (int)blockIdx.x & 7;

    __shared__ float lds_in[3 * T_];                 // normalized s0,s1,c per t (24KB)
    __shared__ float lds_part[NW_ * 3 * JS_];        // per-wave partials (21.5KB)

    // ---- stage normalized inputs for this sequence into LDS (one time) ----
    for (int i = tid; i < T_; i += 1024) {
        const float kn = 2.0f / 255.0f;
        lds_in[3*i+0] = kn * (float)sample[((size_t)s*T_ + i)*2 + 0] - 1.0f;
        lds_in[3*i+1] = kn * (float)sample[((size_t)s*T_ + i)*2 + 1] - 1.0f;
        lds_in[3*i+2] = kn * (float)cts[(size_t)s*T_ + i] - 1.0f;
    }

    // ---- load R slice into registers (one time) ----
    // thread covers gates {u,r,e} x j in {ja, jb} x k in [w*56, w*56+56)
    const bool valid = (lane < 56);
    const int  ja = x*JS_ + (valid ? lane : 0);   // always in-bounds
    const int  jb = ja + 56;
    const int  kb = w * KCH_;
    float Ru0[KCH_], Ru1[KCH_], Rr0[KCH_], Rr1[KCH_], Re0[KCH_], Re1[KCH_];
    {
        const float* pu0 = R + (size_t)ja*H_        + kb;
        const float* pu1 = R + (size_t)jb*H_        + kb;
        const float* pr0 = R + (size_t)(H_+ja)*H_   + kb;
        const float* pr1 = R + (size_t)(H_+jb)*H_   + kb;
        const float* pe0 = R + (size_t)(2*H_+ja)*H_ + kb;
        const float* pe1 = R + (size_t)(2*H_+jb)*H_ + kb;
        #pragma unroll
        for (int kk = 0; kk < KCH_; ++kk) {
            Ru0[kk] = valid ? pu0[kk] : 0.0f;
            Ru1[kk] = valid ? pu1[kk] : 0.0f;
            Rr0[kk] = valid ? pr0[kk] : 0.0f;
            Rr1[kk] = valid ? pr1[kk] : 0.0f;
            Re0[kk] = valid ? pe0[kk] : 0.0f;
            Re1[kk] = valid ? pe1[kk] : 0.0f;
        }
    }

    // ---- gate-thread constants (tid < 112): fwd-projection weights + biases ----
    float wu0=0,wu1=0,wu2=0, wr0=0,wr1=0,wr2=0, we0=0,we1=0,we2=0, gbu=0,gbr=0,gbe=0;
    const int jg = x*JS_ + tid;   // valid only for tid < 112
    if (tid < JS_) {
        if (jg < SUB_) {          // c-path (block-uniform: x < 4)
            wu0 = Wc[2*jg];            wu1 = Wc[2*jg+1];
            wr0 = Wc[2*(SUB_+jg)];     wr1 = Wc[2*(SUB_+jg)+1];
            we0 = Wc[2*(2*SUB_+jg)];   we1 = Wc[2*(2*SUB_+jg)+1];
        } else {                  // f-path (x >= 4)
            const int jf = jg - SUB_;
            wu0 = Wf[3*jf];            wu1 = Wf[3*jf+1];            wu2 = Wf[3*jf+2];
            wr0 = Wf[3*(SUB_+jf)];     wr1 = Wf[3*(SUB_+jf)+1];     wr2 = Wf[3*(SUB_+jf)+2];
            we0 = Wf[3*(2*SUB_+jf)];   we1 = Wf[3*(2*SUB_+jf)+1];   we2 = Wf[3*(2*SUB_+jf)+2];
        }
        gbu = b_u[jg]; gbr = b_r[jg]; gbe = b_e[jg];
    }
    __syncthreads();

    int* const myflags = flags + s * NS_;

    #pragma unroll 1
    for (int t = 1; t <= T_; ++t) {
        // ---- wait until all 8 slices finished step t-1 ----
        if (w == 0) {
            for (;;) {
                int v = (lane < NS_)
                    ? __hip_atomic_load(&myflags[lane], __ATOMIC_RELAXED, __HIP_MEMORY_SCOPE_AGENT)
                    : 0x7fffffff;
                if (__all(v >= t - 1)) break;
                __builtin_amdgcn_s_sleep(1);
            }
            __builtin_amdgcn_fence(__ATOMIC_ACQUIRE, "agent");  // L2 inv: see remote h
        }
        __syncthreads();

        const float* __restrict__ hsrc = hbuf + (size_t)(((t-1)&1)*B_ + s) * H_;

        // ---- matmul partials: r_g[j] += sum_k h[k] * R[g,j,k] ----
        float au0=0.f, au1=0.f, ar0=0.f, ar1=0.f, ae0=0.f, ae1=0.f;
        {
            const float* hp = hsrc + kb;   // wave-uniform chunk
            #pragma unroll
            for (int q = 0; q < KCH_/4; ++q) {
                const float4 h4 = *(const float4*)(hp + 4*q);
                au0 += h4.x*Ru0[4*q+0]; au1 += h4.x*Ru1[4*q+0];
                ar0 += h4.x*Rr0[4*q+0]; ar1 += h4.x*Rr1[4*q+0];
                ae0 += h4.x*Re0[4*q+0]; ae1 += h4.x*Re1[4*q+0];
                au0 += h4.y*Ru0[4*q+1]; au1 += h4.y*Ru1[4*q+1];
                ar0 += h4.y*Rr0[4*q+1]; ar1 += h4.y*Rr1[4*q+1];
                ae0 += h4.y*Re0[4*q+1]; ae1 += h4.y*Re1[4*q+1];
                au0 += h4.z*Ru0[4*q+2]; au1 += h4.z*Ru1[4*q+2];
                ar0 += h4.z*Rr0[4*q+2]; ar1 += h4.z*Rr1[4*q+2];
                ae0 += h4.z*Re0[4*q+2]; ae1 += h4.z*Re1[4*q+2];
                au0 += h4.w*Ru0[4*q+3]; au1 += h4.w*Ru1[4*q+3];
                ar0 += h4.w*Rr0[4*q+3]; ar1 += h4.w*Rr1[4*q+3];
                ae0 += h4.w*Re0[4*q+3]; ae1 += h4.w*Re1[4*q+3];
            }
        }
        if (valid) {
            lds_part[(w*3+0)*JS_ + lane]      = au0;
            lds_part[(w*3+0)*JS_ + lane + 56] = au1;
            lds_part[(w*3+1)*JS_ + lane]      = ar0;
            lds_part[(w*3+1)*JS_ + lane + 56] = ar1;
            lds_part[(w*3+2)*JS_ + lane]      = ae0;
            lds_part[(w*3+2)*JS_ + lane + 56] = ae1;
        }
        __syncthreads();

        // ---- gates + h update (threads 0..111) ----
        if (tid < JS_) {
            float ru = 0.f, rr = 0.f, re = 0.f;
            #pragma unroll
            for (int ww = 0; ww < NW_; ++ww) {
                ru += lds_part[(ww*3+0)*JS_ + tid];
                rr += lds_part[(ww*3+1)*JS_ + tid];
                re += lds_part[(ww*3+2)*JS_ + tid];
            }
            const float s0n = lds_in[3*(t-1)+0];
            const float s1n = lds_in[3*(t-1)+1];
            const float c0n = lds_in[3*(t-1)+2];
            const float fu = s0n*wu0 + s1n*wu1 + c0n*wu2;
            const float fr = s0n*wr0 + s1n*wr1 + c0n*wr2;
            const float fe = s0n*we0 + s1n*we1 + c0n*we2;
            const float ut = 1.0f / (1.0f + __expf(-(ru + fu + gbu)));
            const float rt = 1.0f / (1.0f + __expf(-(rr + fr + gbr)));
            const float et = tanhf(rt*re + fe + gbe);
            const float hp = hsrc[jg];
            const float hn = ut*hp + (1.0f - ut)*et;
            // write-through (agent coherent) store of new h
            __hip_atomic_store(&hbuf[(size_t)((t&1)*B_ + s)*H_ + jg], hn,
                               __ATOMIC_RELAXED, __HIP_MEMORY_SCOPE_AGENT);
            states[((size_t)s*T_ + (t-1))*H_ + jg] = __float2bfloat16(hn);
            if (t == T_) out[(size_t)LAST_OFF + (size_t)s*H_ + jg] = hn;
        }
        __syncthreads();   // drains vmcnt for all waves -> h stores complete
        if (tid == 0) {
            __hip_atomic_store(&myflags[x], t, __ATOMIC_RELAXED, __HIP_MEMORY_SCOPE_AGENT);
        }
    }
}

// ---------------------------------------------------------------------------
// head: per-32-row block, fused relu(W1 x + b1) -> W2 -> log_softmax
// ---------------------------------------------------------------------------
#define HB_ROWS 32

__global__ __launch_bounds__(512)
void wavrnn_head(const __hip_bfloat16* __restrict__ states,
                 const float* __restrict__ Wc1, const float* __restrict__ bc1,
                 const float* __restrict__ Wc2, const float* __restrict__ bc2,
                 const float* __restrict__ Wf1, const float* __restrict__ bf1,
                 const float* __restrict__ Wf2, const float* __restrict__ bf2,
                 float* __restrict__ out)
{
    __shared__ __hip_bfloat16 st[HB_ROWS][H_ + 8];
    __shared__ __hip_bfloat16 a1[HB_ROWS][H_ + 8];
    __shared__ __hip_bfloat16 lg[HB_ROWS][2*Q_ + 8];

    const int tid = (int)threadIdx.x;
    const size_t row0 = (size_t)blockIdx.x * HB_ROWS;

    // stage 32 state rows (bf16)
    for (int i = tid; i < HB_ROWS * (H_/8); i += 512) {
        const int r = i / (H_/8);
        const int c = i % (H_/8);
        *(uint4*)&st[r][c*8] = *(const uint4*)(states + (row0 + r)*H_ + c*8);
    }
    __syncthreads();

    const int r  = tid & 31;
    const int og = tid >> 5;    // 0..15

    // ---- stage A: a1 = relu(W1 @ h_half + b1), both heads ----
    {
        const bool  isF = (og >= 8);
        const float* W1 = isF ? Wf1 : Wc1;
        const float* b1 = isF ? bf1 : bc1;
        const int ob = og * 56;                 // a1 column base in [0,896)
        const int wb = isF ? ob - SUB_ : ob;    // W1 row base in [0,448)
        const int ko = isF ? SUB_ : 0;          // state column offset
        #pragma unroll 1
        for (int oc = 0; oc < 7; ++oc) {
            float acc[8];
            #pragma unroll
            for (int u = 0; u < 8; ++u) acc[u] = b1[wb + oc*8 + u];
            #pragma unroll 2
            for (int k4 = 0; k4 < SUB_/4; ++k4) {
                const ushort4 sv = *(const ushort4*)&st[r][ko + 4*k4];
                const float s0 = bf2f(sv.x), s1 = bf2f(sv.y), s2 = bf2f(sv.z), s3 = bf2f(sv.w);
                #pragma unroll
                for (int u = 0; u < 8; ++u) {
                    const float4 wv = *(const float4*)(W1 + (size_t)(wb + oc*8 + u)*SUB_ + 4*k4);
                    acc[u] += s0*wv.x + s1*wv.y + s2*wv.z + s3*wv.w;
                }
            }
            #pragma unroll
            for (int u = 0; u < 8; ++u)
                a1[r][ob + oc*8 + u] = __float2bfloat16(fmaxf(acc[u], 0.0f));
        }
    }
    __syncthreads();

    // ---- stage B: logits = W2 @ a1_half + b2 ----
    {
        const int head = og >> 3;               // 0=c, 1=f
        const int o32  = (og & 7) * 32;
        const float* W2 = head ? Wf2 : Wc2;
        const float* b2 = head ? bf2 : bc2;
        const int ko = head ? SUB_ : 0;
        #pragma unroll 1
        for (int oc = 0; oc < 4; ++oc) {
            float acc[8];
            #pragma unroll
            for (int u = 0; u < 8; ++u) acc[u] = b2[o32 + oc*8 + u];
            #pragma unroll 2
            for (int k4 = 0; k4 < SUB_/4; ++k4) {
                const ushort4 av = *(const ushort4*)&a1[r][ko + 4*k4];
                const float a0 = bf2f(av.x), a1v = bf2f(av.y), a2 = bf2f(av.z), a3 = bf2f(av.w);
                #pragma unroll
                for (int u = 0; u < 8; ++u) {
                    const float4 wv = *(const float4*)(W2 + (size_t)(o32 + oc*8 + u)*SUB_ + 4*k4);
                    acc[u] += a0*wv.x + a1v*wv.y + a2*wv.z + a3*wv.w;
                }
            }
            #pragma unroll
            for (int u = 0; u < 8; ++u)
                lg[r][head*Q_ + o32 + oc*8 + u] = __float2bfloat16(acc[u]);
        }
    }
    __syncthreads();

    // ---- log_softmax per (head,row), one wave per pair ----
    {
        const int wv = tid >> 6;   // 0..7
        const int ln = tid & 63;
        #pragma unroll 1
        for (int p = wv; p < 2*HB_ROWS; p += 8) {
            const int hh = p >> 5;
            const int rr = p & 31;
            const ushort4 lv = *(const ushort4*)&lg[rr][hh*Q_ + 4*ln];
            const float v0 = bf2f(lv.x), v1 = bf2f(lv.y), v2 = bf2f(lv.z), v3 = bf2f(lv.w);
            float m = fmaxf(fmaxf(v0, v1), fmaxf(v2, v3));
            #pragma unroll
            for (int d = 1; d < 64; d <<= 1) m = fmaxf(m, __shfl_xor(m, d));
            float sm = __expf(v0-m) + __expf(v1-m) + __expf(v2-m) + __expf(v3-m);
            #pragma unroll
            for (int d = 1; d < 64; d <<= 1) sm += __shfl_xor(sm, d);
            const float ls = m + __logf(sm);
            float* o = out + (hh ? (size_t)FT_OFF : (size_t)0) + (row0 + rr)*Q_ + 4*ln;
            o[0] = v0 - ls; o[1] = v1 - ls; o[2] = v2 - ls; o[3] = v3 - ls;
        }
    }
}

// ---------------------------------------------------------------------------
extern "C" void kernel_launch(void* const* d_in, const int* in_sizes, int n_in,
                              void* d_out, int out_size, void* d_ws, size_t ws_size,
                              hipStream_t stream) {
    const int*   sample = (const int*)d_in[0];
    const int*   cts    = (const int*)d_in[1];
    const float* state  = (const float*)d_in[2];
    const float* R      = (const float*)d_in[3];
    const float* Wc     = (const float*)d_in[4];
    const float* Wf     = (const float*)d_in[5];
    const float* b_u    = (const float*)d_in[6];
    const float* b_r    = (const float*)d_in[7];
    const float* b_e    = (const float*)d_in[8];
    const float* Wc1    = (const float*)d_in[9];
    const float* bc1    = (const float*)d_in[10];
    const float* Wc2    = (const float*)d_in[11];
    const float* bc2    = (const float*)d_in[12];
    const float* Wf1    = (const float*)d_in[13];
    const float* bf1    = (const float*)d_in[14];
    const float* Wf2    = (const float*)d_in[15];
    const float* bf2    = (const float*)d_in[16];

    float* out = (float*)d_out;
    float* hbuf = (float*)d_ws;
    int*   flags = (int*)((char*)d_ws + FLAGS_BOFF);
    __hip_bfloat16* states = (__hip_bfloat16*)((char*)d_ws + STATES_BOFF);

    wavrnn_init<<<114, 256, 0, stream>>>(state, hbuf, flags);
    wavrnn_scan<<<B_ * NS_, 1024, 0, stream>>>(sample, cts, R, Wc, Wf, b_u, b_r, b_e,
                                               hbuf, flags, states, out);
    wavrnn_head<<<(B_ * T_) / HB_ROWS, 512, 0, stream>>>(states, Wc1, bc1, Wc2, bc2,
                                                         Wf1, bf1, Wf2, bf2, out);
}

// Round 2
// 18782.608 us; speedup vs baseline: 12.8158x; 12.8158x over previous
//
#include <hip/hip_runtime.h>
#include <hip/hip_bf16.h>

// Problem constants
#define B_   32
#define T_   2000
#define H_   896
#define SUB_ 448
#define Q_   256

// d_out layout (floats): ct [32,2000,256], ft [32,2000,256], last [32,1,896]
#define FT_OFF   16384000
#define LAST_OFF 32768000

// scan decomposition: 28 blocks x 192 threads (3 waves, 1 wave/SIMD)
#define NBLK_ 28
#define JS_   32          // j columns per block
#define NW_   3           // waves per block = gates
#define NCH_  56          // K chunks of 16 (896/16)

// d_ws layout (bytes) -- keep total <= round-1 usage (~114.95 MB)
#define H0_BOFF     0          // bf16 [32][896] : 57344 B
#define FLAGS_BOFF  57344      // int [28]
#define STATES_BOFF 65536      // bf16 [32][2000][896] : 114688000 B

typedef __attribute__((ext_vector_type(8)))  short bf16x8;
typedef __attribute__((ext_vector_type(16))) float f32x16;

__device__ __forceinline__ unsigned short f2bf(float f) {
    unsigned int u = __builtin_bit_cast(unsigned int, f);
    u += 0x7fff + ((u >> 16) & 1);          // RNE
    return (unsigned short)(u >> 16);
}
__device__ __forceinline__ float bf2f(unsigned short u) {
    return __builtin_bit_cast(float, (unsigned int)u << 16);
}

__device__ __forceinline__ void gload_lds16(const void* g, void* l) {
    __builtin_amdgcn_global_load_lds(
        (const __attribute__((address_space(1))) unsigned int*)g,
        (__attribute__((address_space(3))) unsigned int*)l, 16, 0, 0);
}

// ---------------------------------------------------------------------------
// init: h0 = bf16(state), flags = 0
// ---------------------------------------------------------------------------
__global__ void wavrnn_init2(const float* __restrict__ state,
                             unsigned short* __restrict__ h0,
                             int* __restrict__ flags) {
    const int i = blockIdx.x * 256 + threadIdx.x;
    if (i < B_ * H_) h0[i] = f2bf(state[i]);
    if (i < NBLK_) flags[i] = 0;
}

// ---------------------------------------------------------------------------
// scan v2: R register-resident once (batched over all 32 sequences),
// MFMA recurrence, global flag barrier across 28 blocks per step.
// ---------------------------------------------------------------------------
__global__ __launch_bounds__(192, 1)
void wavrnn_scan2(const int* __restrict__ sample, const int* __restrict__ cts,
                  const float* __restrict__ state, const float* __restrict__ R,
                  const float* __restrict__ Wc, const float* __restrict__ Wf,
                  const float* __restrict__ b_u, const float* __restrict__ b_r,
                  const float* __restrict__ b_e,
                  const unsigned short* __restrict__ h0,   // bf16 bits
                  int* __restrict__ flags,
                  unsigned short* __restrict__ states,     // bf16 bits [32][2000][896]
                  float* __restrict__ out)
{
    const int tid  = (int)threadIdx.x;
    const int w    = tid >> 6;        // wave = gate (0:u, 1:r, 2:e)
    const int lane = tid & 63;
    const int s31  = lane & 31;       // m / s index inside fragments
    const int hi   = lane >> 5;       // k-group half
    const int b    = (int)blockIdx.x;

    __shared__ __align__(16) char Abuf[NCH_ * 1024];   // fragment-ordered h tile
    __shared__ float gate_out[3][32][33];              // [gate][s][j] padded

    // ---- register-resident B fragments: wave w holds R rows gate w, j-slice ----
    // B-frag layout (32x32x16): lane l holds B[k = 4*hi + (e&3) + 8*(e>>2)][n = l&31]
    const int jl  = s31;
    const int jgB = b * JS_ + jl;
    bf16x8 Bf[NCH_];
    {
        const float* Rrow = R + (size_t)(w * H_ + jgB) * H_;
        #pragma unroll
        for (int c = 0; c < NCH_; ++c) {
            const float4 p0 = *(const float4*)(Rrow + 16*c + 4*hi);
            const float4 p1 = *(const float4*)(Rrow + 16*c + 8 + 4*hi);
            bf16x8 f;
            f[0] = (short)f2bf(p0.x); f[1] = (short)f2bf(p0.y);
            f[2] = (short)f2bf(p0.z); f[3] = (short)f2bf(p0.w);
            f[4] = (short)f2bf(p1.x); f[5] = (short)f2bf(p1.y);
            f[6] = (short)f2bf(p1.z); f[7] = (short)f2bf(p1.w);
            Bf[c] = f;
        }
    }

    // ---- gate-thread setup (tid<128): 2 j x 4 s per thread ----
    const int jp  = tid & 15;          // j-pair
    const int sg  = (tid >> 4) & 7;    // s-group
    const int j0  = 2 * jp;
    const int jg0 = b * JS_ + j0;
    float wu[2][3], wr[2][3], we[2][3], gb[2][3];
    float hreg[4][2];                  // fp32 h_old, register-resident
    if (tid < 128) {
        #pragma unroll
        for (int jj = 0; jj < 2; ++jj) {
            const int jg = jg0 + jj;
            if (jg < SUB_) {
                wu[jj][0]=Wc[2*jg];            wu[jj][1]=Wc[2*jg+1];            wu[jj][2]=0.f;
                wr[jj][0]=Wc[2*(SUB_+jg)];     wr[jj][1]=Wc[2*(SUB_+jg)+1];     wr[jj][2]=0.f;
                we[jj][0]=Wc[2*(2*SUB_+jg)];   we[jj][1]=Wc[2*(2*SUB_+jg)+1];   we[jj][2]=0.f;
            } else {
                const int jf = jg - SUB_;
                wu[jj][0]=Wf[3*jf];            wu[jj][1]=Wf[3*jf+1];            wu[jj][2]=Wf[3*jf+2];
                wr[jj][0]=Wf[3*(SUB_+jf)];     wr[jj][1]=Wf[3*(SUB_+jf)+1];     wr[jj][2]=Wf[3*(SUB_+jf)+2];
                we[jj][0]=Wf[3*(2*SUB_+jf)];   we[jj][1]=Wf[3*(2*SUB_+jf)+1];   we[jj][2]=Wf[3*(2*SUB_+jf)+2];
            }
            gb[jj][0]=b_u[jg]; gb[jj][1]=b_r[jg]; gb[jj][2]=b_e[jg];
        }
        #pragma unroll
        for (int q = 0; q < 4; ++q) {
            const int s = sg*4 + q;
            hreg[q][0] = state[(size_t)s*H_ + jg0];
            hreg[q][1] = state[(size_t)s*H_ + jg0 + 1];
        }
    }
    __syncthreads();

    const int aoff = s31*16 + 8*hi;

    #pragma unroll 1
    for (int t = 1; t <= T_; ++t) {
        // ---- global barrier: all 28 blocks done with step t-1 ----
        if (w == 0) {
            for (;;) {
                int v = (lane < NBLK_)
                    ? __hip_atomic_load(&flags[lane], __ATOMIC_RELAXED, __HIP_MEMORY_SCOPE_AGENT)
                    : 0x7fffffff;
                if (__all(v >= t - 1)) break;
                __builtin_amdgcn_s_sleep(2);
            }
            __builtin_amdgcn_fence(__ATOMIC_ACQUIRE, "agent");
        }
        __syncthreads();

        // ---- stage h(t-1) (bf16, all 32 seqs) fragment-ordered into LDS ----
        // lane l fetches 16B = h[s=l&31][16c + 8*hi .. +8); dest = Abuf + c*1024 + l*16
        {
            const char* srcbase = (t == 1)
                ? (const char*)h0 + (size_t)s31 * (H_ * 2)
                : (const char*)states + ((size_t)s31 * T_ + (size_t)(t - 2)) * (H_ * 2);
            for (int c = w; c < NCH_; c += NW_)
                gload_lds16(srcbase + c*32 + hi*16, Abuf + c*1024);
        }

        // ---- per-step inputs (hidden under staging latency) ----
        float s0n[4], s1n[4], c0n[4];
        if (tid < 128) {
            const float kn = 2.0f / 255.0f;
            #pragma unroll
            for (int q = 0; q < 4; ++q) {
                const size_t idx = (size_t)(sg*4 + q)*T_ + (size_t)(t - 1);
                const int2 sv = *(const int2*)(sample + idx*2);
                s0n[q] = kn*(float)sv.x - 1.0f;
                s1n[q] = kn*(float)sv.y - 1.0f;
                c0n[q] = kn*(float)cts[idx] - 1.0f;
            }
        }
        __syncthreads();   // staging complete (per-wave vmcnt drained at barrier)

        // ---- MFMA: D[s][j] = sum_k h[s][k] * R[gate w][j][k] ----
        f32x16 acc;
        #pragma unroll
        for (int e = 0; e < 16; ++e) acc[e] = 0.0f;
        #pragma unroll
        for (int c = 0; c < NCH_; ++c) {
            const short4 a0 = *(const short4*)(Abuf + c*1024 + aoff);
            const short4 a1 = *(const short4*)(Abuf + c*1024 + aoff + 512);
            bf16x8 af;
            af[0]=a0.x; af[1]=a0.y; af[2]=a0.z; af[3]=a0.w;
            af[4]=a1.x; af[5]=a1.y; af[6]=a1.z; af[7]=a1.w;
            acc = __builtin_amdgcn_mfma_f32_32x32x16_bf16(af, Bf[c], acc, 0, 0, 0);
        }
        // C/D layout (verified m74/m101): col=lane&31, row=(e&3)+8*(e>>2)+4*hi
        #pragma unroll
        for (int e = 0; e < 16; ++e) {
            const int srow = (e & 3) + 8*(e >> 2) + 4*hi;
            gate_out[w][srow][jl] = acc[e];
        }
        __syncthreads();

        // ---- gates + h update (fp32 state in registers) ----
        if (tid < 128) {
            #pragma unroll
            for (int q = 0; q < 4; ++q) {
                const int s = sg*4 + q;
                unsigned int packed = 0;
                #pragma unroll
                for (int jj = 0; jj < 2; ++jj) {
                    const int j = j0 + jj;
                    const float ru = gate_out[0][s][j];
                    const float rr = gate_out[1][s][j];
                    const float re = gate_out[2][s][j];
                    const float fu = s0n[q]*wu[jj][0] + s1n[q]*wu[jj][1] + c0n[q]*wu[jj][2];
                    const float fr = s0n[q]*wr[jj][0] + s1n[q]*wr[jj][1] + c0n[q]*wr[jj][2];
                    const float fe = s0n[q]*we[jj][0] + s1n[q]*we[jj][1] + c0n[q]*we[jj][2];
                    const float ut = 1.0f/(1.0f + __expf(-(ru + fu + gb[jj][0])));
                    const float rt = 1.0f/(1.0f + __expf(-(rr + fr + gb[jj][1])));
                    const float et = tanhf(rt*re + fe + gb[jj][2]);
                    const float hn = ut*hreg[q][jj] + (1.0f - ut)*et;
                    hreg[q][jj] = hn;
                    packed |= (unsigned int)f2bf(hn) << (16*jj);
                    if (t == T_) out[LAST_OFF + (size_t)s*H_ + jg0 + jj] = hn;
                }
                // agent-scope 4B store: h(t) visible to all XCDs
                __hip_atomic_store(
                    (unsigned int*)(states + ((size_t)s*T_ + (size_t)(t-1))*H_ + jg0),
                    packed, __ATOMIC_RELAXED, __HIP_MEMORY_SCOPE_AGENT);
            }
        }
        __syncthreads();   // drains all waves' stores (vmcnt(0) at barrier)
        if (tid == 0)
            __hip_atomic_store(&flags[b], t, __ATOMIC_RELAXED, __HIP_MEMORY_SCOPE_AGENT);
    }
}

// ---------------------------------------------------------------------------
// head: per-32-row block, fused relu(W1 x + b1) -> W2 -> log_softmax
// (unchanged from round 1 -- validated)
// ---------------------------------------------------------------------------
#define HB_ROWS 32

__global__ __launch_bounds__(512)
void wavrnn_head(const __hip_bfloat16* __restrict__ states,
                 const float* __restrict__ Wc1, const float* __restrict__ bc1,
                 const float* __restrict__ Wc2, const float* __restrict__ bc2,
                 const float* __restrict__ Wf1, const float* __restrict__ bf1,
                 const float* __restrict__ Wf2, const float* __restrict__ bf2,
                 float* __restrict__ out)
{
    __shared__ __hip_bfloat16 st[HB_ROWS][H_ + 8];
    __shared__ __hip_bfloat16 a1[HB_ROWS][H_ + 8];
    __shared__ __hip_bfloat16 lg[HB_ROWS][2*Q_ + 8];

    const int tid = (int)threadIdx.x;
    const size_t row0 = (size_t)blockIdx.x * HB_ROWS;

    for (int i = tid; i < HB_ROWS * (H_/8); i += 512) {
        const int r = i / (H_/8);
        const int c = i % (H_/8);
        *(uint4*)&st[r][c*8] = *(const uint4*)(states + (row0 + r)*H_ + c*8);
    }
    __syncthreads();

    const int r  = tid & 31;
    const int og = tid >> 5;    // 0..15

    {
        const bool  isF = (og >= 8);
        const float* W1 = isF ? Wf1 : Wc1;
        const float* b1 = isF ? bf1 : bc1;
        const int ob = og * 56;
        const int wb = isF ? ob - SUB_ : ob;
        const int ko = isF ? SUB_ : 0;
        #pragma unroll 1
        for (int oc = 0; oc < 7; ++oc) {
            float acc[8];
            #pragma unroll
            for (int u = 0; u < 8; ++u) acc[u] = b1[wb + oc*8 + u];
            #pragma unroll 2
            for (int k4 = 0; k4 < SUB_/4; ++k4) {
                const ushort4 sv = *(const ushort4*)&st[r][ko + 4*k4];
                const float s0 = bf2f(sv.x), s1 = bf2f(sv.y), s2 = bf2f(sv.z), s3 = bf2f(sv.w);
                #pragma unroll
                for (int u = 0; u < 8; ++u) {
                    const float4 wv = *(const float4*)(W1 + (size_t)(wb + oc*8 + u)*SUB_ + 4*k4);
                    acc[u] += s0*wv.x + s1*wv.y + s2*wv.z + s3*wv.w;
                }
            }
            #pragma unroll
            for (int u = 0; u < 8; ++u)
                a1[r][ob + oc*8 + u] = __float2bfloat16(fmaxf(acc[u], 0.0f));
        }
    }
    __syncthreads();

    {
        const int head = og >> 3;
        const int o32  = (og & 7) * 32;
        const float* W2 = head ? Wf2 : Wc2;
        const float* b2 = head ? bf2 : bc2;
        const int ko = head ? SUB_ : 0;
        #pragma unroll 1
        for (int oc = 0; oc < 4; ++oc) {
            float acc[8];
            #pragma unroll
            for (int u = 0; u < 8; ++u) acc[u] = b2[o32 + oc*8 + u];
            #pragma unroll 2
            for (int k4 = 0; k4 < SUB_/4; ++k4) {
                const ushort4 av = *(const ushort4*)&a1[r][ko + 4*k4];
                const float a0 = bf2f(av.x), a1v = bf2f(av.y), a2 = bf2f(av.z), a3 = bf2f(av.w);
                #pragma unroll
                for (int u = 0; u < 8; ++u) {
                    const float4 wv = *(const float4*)(W2 + (size_t)(o32 + oc*8 + u)*SUB_ + 4*k4);
                    acc[u] += a0*wv.x + a1v*wv.y + a2*wv.z + a3*wv.w;
                }
            }
            #pragma unroll
            for (int u = 0; u < 8; ++u)
                lg[r][head*Q_ + o32 + oc*8 + u] = __float2bfloat16(acc[u]);
        }
    }
    __syncthreads();

    {
        const int wv = tid >> 6;
        const int ln = tid & 63;
        #pragma unroll 1
        for (int p = wv; p < 2*HB_ROWS; p += 8) {
            const int hh = p >> 5;
            const int rr = p & 31;
            const ushort4 lv = *(const ushort4*)&lg[rr][hh*Q_ + 4*ln];
            const float v0 = bf2f(lv.x), v1 = bf2f(lv.y), v2 = bf2f(lv.z), v3 = bf2f(lv.w);
            float m = fmaxf(fmaxf(v0, v1), fmaxf(v2, v3));
            #pragma unroll
            for (int d = 1; d < 64; d <<= 1) m = fmaxf(m, __shfl_xor(m, d));
            float sm = __expf(v0-m) + __expf(v1-m) + __expf(v2-m) + __expf(v3-m);
            #pragma unroll
            for (int d = 1; d < 64; d <<= 1) sm += __shfl_xor(sm, d);
            const float ls = m + __logf(sm);
            float* o = out + (hh ? (size_t)FT_OFF : (size_t)0) + (row0 + rr)*Q_ + 4*ln;
            o[0] = v0 - ls; o[1] = v1 - ls; o[2] = v2 - ls; o[3] = v3 - ls;
        }
    }
}

// ---------------------------------------------------------------------------
extern "C" void kernel_launch(void* const* d_in, const int* in_sizes, int n_in,
                              void* d_out, int out_size, void* d_ws, size_t ws_size,
                              hipStream_t stream) {
    (void)in_sizes; (void)n_in; (void)out_size; (void)ws_size;
    const int*   sample = (const int*)d_in[0];
    const int*   cts    = (const int*)d_in[1];
    const float* state  = (const float*)d_in[2];
    const float* R      = (const float*)d_in[3];
    const float* Wc     = (const float*)d_in[4];
    const float* Wf     = (const float*)d_in[5];
    const float* b_u    = (const float*)d_in[6];
    const float* b_r    = (const float*)d_in[7];
    const float* b_e    = (const float*)d_in[8];
    const float* Wc1    = (const float*)d_in[9];
    const float* bc1    = (const float*)d_in[10];
    const float* Wc2    = (const float*)d_in[11];
    const float* bc2    = (const float*)d_in[12];
    const float* Wf1    = (const float*)d_in[13];
    const float* bf1    = (const float*)d_in[14];
    const float* Wf2    = (const float*)d_in[15];
    const float* bf2    = (const float*)d_in[16];

    float* out = (float*)d_out;
    unsigned short* h0     = (unsigned short*)((char*)d_ws + H0_BOFF);
    int*            flags  = (int*)((char*)d_ws + FLAGS_BOFF);
    unsigned short* states = (unsigned short*)((char*)d_ws + STATES_BOFF);

    wavrnn_init2<<<112, 256, 0, stream>>>(state, h0, flags);
    wavrnn_scan2<<<NBLK_, 192, 0, stream>>>(sample, cts, state, R, Wc, Wf,
                                            b_u, b_r, b_e, h0, flags, states, out);
    wavrnn_head<<<(B_ * T_) / HB_ROWS, 512, 0, stream>>>(
        (const __hip_bfloat16*)states, Wc1, bc1, Wc2, bc2, Wf1, bf1, Wf2, bf2, out);
}